// Round 9
// baseline (801.568 us; speedup 1.0000x reference)
//
#include <hip/hip_runtime.h>

// Chamfer distance, B=8, N=M=8192, D=3, fp32 — fused MFMA formulation.
// fp32 split into f16 hi+lo (x = xh+xl, err ~2^-22). K=16 vectors (see R5).
// One v_mfma_f32_32x32x16_f16 = 32x32 tile of d(n,m)=sq_n+sq_m-2<a,c>.
// R9 (LDS-pipe diet): (1) per-wave PRIVATE d2 planes, plain ds_write_b32
// (each column written exactly once per wave — no atomics, no init);
// (2) each wave runs TWO row-groups against one B-frag ds_read (halves
// reads and d2 writes); (3) halves merged via shfl_xor(32) before write.
// C/D: col=lane&31, row=(reg&3)+8*(reg>>2)+4*(lane>>5)  [HW-verified]
// A/B: row/col=lane&31, k=(lane>>5)*8+j                 [verified R5: absmax 0]

typedef _Float16 half8 __attribute__((ext_vector_type(8)));
typedef float    f16x  __attribute__((ext_vector_type(16)));

constexpr int B      = 8;
constexpr int NPTS   = 8192;
constexpr int TOTAL  = B * NPTS;      // 65536
constexpr int NSTRIP = 256;           // n-rows per block (4 waves * 2 groups * 32)
constexpr int NSTR   = NPTS / NSTRIP; // 32 strips
constexpr int MHALF  = 2048;          // m-range per block
constexpr int NMH    = NPTS / MHALF;  // 4
constexpr int CHUNK  = 256;           // m staged in LDS per chunk
constexpr int NCHUNK = MHALF / CHUNK; // 8

// min3 tree: min of 16 C-regs (column-min within a lane), 8 issues.
__device__ __forceinline__ float colmin16(const f16x& a)
{
    float m0 = fminf(fminf(a[0],  a[1]),  a[2]);
    float m1 = fminf(fminf(a[3],  a[4]),  a[5]);
    float m2 = fminf(fminf(a[6],  a[7]),  a[8]);
    float m3 = fminf(fminf(a[9],  a[10]), a[11]);
    float m4 = fminf(fminf(a[12], a[13]), a[14]);
    return fminf(fminf(fminf(m0, m1), m2), fminf(fminf(m3, m4), a[15]));
}

__device__ __forceinline__ void pack_b(const float* __restrict__ cp,
                                       half8& lo, half8& hi)
{
    float cx = cp[0], cy = cp[1], cz = cp[2];
    float x = -2.f * cx, y = -2.f * cy, z = -2.f * cz;
    float sq = fmaf(cx, cx, fmaf(cy, cy, cz * cz));
    _Float16 xh = (_Float16)x, yh = (_Float16)y, zh = (_Float16)z;
    _Float16 xl = (_Float16)(x - (float)xh);
    _Float16 yl = (_Float16)(y - (float)yh);
    _Float16 zl = (_Float16)(z - (float)zh);
    _Float16 sh = (_Float16)sq, sl = (_Float16)(sq - (float)sh);
    lo = half8{xh, yh, zh, xh, yh, zh, xl, yl};
    hi = half8{zl, (_Float16)1.f, (_Float16)1.f, sh, sl,
               (_Float16)0.f, (_Float16)0.f, (_Float16)0.f};
}

__device__ __forceinline__ half8 pack_a(const float* __restrict__ a, int half)
{
    float x = a[0], y = a[1], z = a[2];
    float sq = fmaf(x, x, fmaf(y, y, z * z));
    _Float16 xh = (_Float16)x, yh = (_Float16)y, zh = (_Float16)z;
    _Float16 xl = (_Float16)(x - (float)xh);
    _Float16 yl = (_Float16)(y - (float)yh);
    _Float16 zl = (_Float16)(z - (float)zh);
    _Float16 sh = (_Float16)sq, sl = (_Float16)(sq - (float)sh);
    half8 lo = {xh, yh, zh, xl, yl, zl, xh, yh};
    half8 hi = {zh, sh, sl, (_Float16)1.f, (_Float16)1.f,
                (_Float16)0.f, (_Float16)0.f, (_Float16)0.f};
    return half ? hi : lo;
}

// grid (32, 4, 8), block 256 (4 waves, each owning rows {g0, g0+128}).
// dist1 (min over m) in regs -> d1p[b][mh][n]  (unclamped).
// dist2 (min over n) via wave-private LDS planes -> d2p[b][strip][m] (clamped).
__global__ __launch_bounds__(256, 4) void chamfer_mfma(
    const float* __restrict__ in1, const float* __restrict__ in2,
    float* __restrict__ d1p, float* __restrict__ d2p, float* __restrict__ out)
{
    const int b     = blockIdx.z;
    const int strip = blockIdx.x;
    const int mh    = blockIdx.y;
    const int wave  = threadIdx.x >> 6;
    const int lane  = threadIdx.x & 63;
    const int col   = lane & 31;
    const int half  = lane >> 5;

    if ((blockIdx.x | blockIdx.y | blockIdx.z) == 0 && threadIdx.x == 0)
        *out = 0.0f;                   // zero accumulator before reduce runs

    __shared__ _Float16 ldsLo[CHUNK * 8];      // 4 KiB
    __shared__ _Float16 ldsHi[CHUNK * 8];      // 4 KiB
    __shared__ float    d2w[4][MHALF];         // 32 KiB, wave-private planes

    // Two A fragments per wave: rows nbase0.. and nbase0+128..
    const int nbase0 = strip * NSTRIP + wave * 32;
    const int nbase1 = nbase0 + 128;
    half8 afrag0 = pack_a(in1 + ((size_t)b * NPTS + nbase0 + col) * 3, half);
    half8 afrag1 = pack_a(in1 + ((size_t)b * NPTS + nbase1 + col) * 3, half);

    f16x MN0, MN1, zero;
#pragma unroll
    for (int r = 0; r < 16; ++r) { MN0[r] = 1e30f; MN1[r] = 1e30f; zero[r] = 0.0f; }

    const float* Craw = in2 + ((size_t)b * NPTS + mh * MHALF) * 3;

    // Pipelined pack: regs hold chunk c's packed point (1 per thread).
    half8 lo0, hi0;
    pack_b(Craw + (size_t)threadIdx.x * 3, lo0, hi0);

    for (int c = 0; c < NCHUNK; ++c) {
        __syncthreads();               // previous chunk's compute done
        *(half8*)&ldsLo[threadIdx.x * 8] = lo0;
        *(half8*)&ldsHi[threadIdx.x * 8] = hi0;
        __syncthreads();

        if (c + 1 < NCHUNK)            // next chunk's loads overlap compute
            pack_b(Craw + (size_t)((c + 1) * CHUNK + threadIdx.x) * 3, lo0, hi0);

        const _Float16* fragBase = half ? ldsHi : ldsLo;
#pragma unroll
        for (int t = 0; t < CHUNK / 32; ++t) {
            half8 bf = *(const half8*)&fragBase[(t * 32 + col) * 8];
            f16x acc0 = __builtin_amdgcn_mfma_f32_32x32x16_f16(afrag0, bf, zero, 0, 0, 0);
            f16x acc1 = __builtin_amdgcn_mfma_f32_32x32x16_f16(afrag1, bf, zero, 0, 0, 0);

            // dist1: per-reg running min across m (separate row-groups).
#pragma unroll
            for (int r = 0; r < 16; ++r) {
                MN0[r] = fminf(MN0[r], acc0[r]);
                MN1[r] = fminf(MN1[r], acc1[r]);
            }

            // dist2: column-min over both row-groups, merge halves via
            // shfl, single plain write to the wave's private plane.
            float v = fminf(colmin16(acc0), colmin16(acc1));
            v = fminf(v, __shfl_xor(v, 32, 64));
            if (half == 0)
                d2w[wave][c * CHUNK + t * 32 + col] = v;
        }
    }
    __syncthreads();

    // Block merge of the 4 wave-planes -> global d2 (clamped).
    {
        const int i0 = threadIdx.x * 8;            // 8 cols per thread
        float4 a0 = *(const float4*)&d2w[0][i0];
        float4 a1 = *(const float4*)&d2w[1][i0];
        float4 a2 = *(const float4*)&d2w[2][i0];
        float4 a3 = *(const float4*)&d2w[3][i0];
        float4 m;
        m.x = fmaxf(fminf(fminf(a0.x, a1.x), fminf(a2.x, a3.x)), 0.0f);
        m.y = fmaxf(fminf(fminf(a0.y, a1.y), fminf(a2.y, a3.y)), 0.0f);
        m.z = fmaxf(fminf(fminf(a0.z, a1.z), fminf(a2.z, a3.z)), 0.0f);
        m.w = fmaxf(fminf(fminf(a0.w, a1.w), fminf(a2.w, a3.w)), 0.0f);
        float4 b0 = *(const float4*)&d2w[0][i0 + 4];
        float4 b1 = *(const float4*)&d2w[1][i0 + 4];
        float4 b2 = *(const float4*)&d2w[2][i0 + 4];
        float4 b3 = *(const float4*)&d2w[3][i0 + 4];
        float4 n2;
        n2.x = fmaxf(fminf(fminf(b0.x, b1.x), fminf(b2.x, b3.x)), 0.0f);
        n2.y = fmaxf(fminf(fminf(b0.y, b1.y), fminf(b2.y, b3.y)), 0.0f);
        n2.z = fmaxf(fminf(fminf(b0.z, b1.z), fminf(b2.z, b3.z)), 0.0f);
        n2.w = fmaxf(fminf(fminf(b0.w, b1.w), fminf(b2.w, b3.w)), 0.0f);
        float* d2 = d2p + ((size_t)b * NSTR + strip) * NPTS + mh * MHALF;
        *(float4*)&d2[i0]     = m;
        *(float4*)&d2[i0 + 4] = n2;
    }

    // dist1: butterfly min across the 32 cols of each half, lane 0 of each
    // half writes its 16 rows: row = (r&3) + 8*(r>>2) + 4*half.
#pragma unroll
    for (int m = 1; m <= 16; m <<= 1)
#pragma unroll
        for (int r = 0; r < 16; ++r) {
            MN0[r] = fminf(MN0[r], __shfl_xor(MN0[r], m, 64));
            MN1[r] = fminf(MN1[r], __shfl_xor(MN1[r], m, 64));
        }
    if (col == 0) {
        float* d1 = d1p + ((size_t)b * NMH + mh) * NPTS;
#pragma unroll
        for (int r = 0; r < 16; ++r) {
            int row = (r & 3) + 8 * (r >> 2) + 4 * half;
            d1[nbase0 + row] = MN0[r];
            d1[nbase1 + row] = MN1[r];
        }
    }
}

// One thread per 4 m's: fold 32 d2 strip-planes (pre-clamped) + 4 d1
// planes (clamp here), sum, wave-reduce, atomicAdd(out, sum/TOTAL).
__global__ __launch_bounds__(256) void reduce_kernel(
    const float* __restrict__ d1p, const float* __restrict__ d2p,
    float* __restrict__ out)
{
    int g  = blockIdx.x * 256 + threadIdx.x;      // [0, TOTAL/4)
    int b  = g >> 11;
    int mq = g & 2047;                            // float4 index within batch

    const float4* p2 = (const float4*)(d2p + (size_t)b * NSTR * NPTS) + mq;
    float4 v2 = p2[0];
#pragma unroll
    for (int s = 1; s < NSTR; ++s) {
        float4 t = p2[(size_t)s * (NPTS / 4)];
        v2.x = fminf(v2.x, t.x); v2.y = fminf(v2.y, t.y);
        v2.z = fminf(v2.z, t.z); v2.w = fminf(v2.w, t.w);
    }
    float4 a0 = ((const float4*)(d1p + ((size_t)b * NMH + 0) * NPTS))[mq];
    float4 a1 = ((const float4*)(d1p + ((size_t)b * NMH + 1) * NPTS))[mq];
    float4 a2 = ((const float4*)(d1p + ((size_t)b * NMH + 2) * NPTS))[mq];
    float4 a3 = ((const float4*)(d1p + ((size_t)b * NMH + 3) * NPTS))[mq];
    float v = fmaxf(fminf(fminf(a0.x, a1.x), fminf(a2.x, a3.x)), 0.0f)
            + fmaxf(fminf(fminf(a0.y, a1.y), fminf(a2.y, a3.y)), 0.0f)
            + fmaxf(fminf(fminf(a0.z, a1.z), fminf(a2.z, a3.z)), 0.0f)
            + fmaxf(fminf(fminf(a0.w, a1.w), fminf(a2.w, a3.w)), 0.0f)
            + v2.x + v2.y + v2.z + v2.w;

#pragma unroll
    for (int off = 32; off; off >>= 1)
        v += __shfl_down(v, off, 64);
    __shared__ float wsum[4];
    int lane = threadIdx.x & 63, w = threadIdx.x >> 6;
    if (lane == 0) wsum[w] = v;
    __syncthreads();
    if (threadIdx.x == 0)
        atomicAdd(out, (wsum[0] + wsum[1] + wsum[2] + wsum[3]) *
                           (1.0f / (float)TOTAL));
}

extern "C" void kernel_launch(void* const* d_in, const int* in_sizes, int n_in,
                              void* d_out, int out_size, void* d_ws, size_t ws_size,
                              hipStream_t stream)
{
    const float* in1 = (const float*)d_in[0];
    const float* in2 = (const float*)d_in[1];
    float* out = (float*)d_out;

    char* ws = (char*)d_ws;
    float* d1p = (float*)ws;                              // 8*4*8192*4 = 1 MiB
    float* d2p = (float*)(ws + (size_t)NMH * TOTAL * 4);  // 8*32*8192*4 = 8 MiB

    chamfer_mfma<<<dim3(NPTS / NSTRIP, NMH, B), 256, 0, stream>>>(
        in1, in2, d1p, d2p, out);
    reduce_kernel<<<TOTAL / 1024, 256, 0, stream>>>(d1p, d2p, out);
}

// Round 10
// 166.060 us; speedup vs baseline: 4.8270x; 4.8270x over previous
//
#include <hip/hip_runtime.h>

// Chamfer distance, B=8, N=M=8192, D=3, fp32 — fused MFMA formulation.
// fp32 split into f16 hi+lo (x = xh+xl, err ~2^-22). K=16 vectors (see R5).
// One v_mfma_f32_32x32x16_f16 = 32x32 tile of d(n,m)=sq_n+sq_m-2<a,c>.
// R10: R9's structure minus the spill trigger — NO forced min-waves bound
// (R9's __launch_bounds__(256,4) caused scratch spill: 1.7 GB writes),
// and dist2 goes straight to per-wave GLOBAL planes (no d2w LDS, no
// atomics: each column produced exactly once per wave).
// C/D: col=lane&31, row=(reg&3)+8*(reg>>2)+4*(lane>>5)  [HW-verified]
// A/B: row/col=lane&31, k=(lane>>5)*8+j                 [verified R5: absmax 0]

typedef _Float16 half8 __attribute__((ext_vector_type(8)));
typedef float    f16x  __attribute__((ext_vector_type(16)));

constexpr int B      = 8;
constexpr int NPTS   = 8192;
constexpr int TOTAL  = B * NPTS;      // 65536
constexpr int NSTRIP = 256;           // n-rows per block (4 waves * 2 groups * 32)
constexpr int NSTR   = NPTS / NSTRIP; // 32 strips
constexpr int NPL    = NSTR * 4;      // 128 dist2 planes per batch (per-wave)
constexpr int MHALF  = 2048;          // m-range per block
constexpr int NMH    = NPTS / MHALF;  // 4
constexpr int CHUNK  = 256;           // m staged in LDS per chunk
constexpr int NCHUNK = MHALF / CHUNK; // 8

// min3 tree: min of 16 C-regs (column-min within a lane), 8 issues.
__device__ __forceinline__ float colmin16(const f16x& a)
{
    float m0 = fminf(fminf(a[0],  a[1]),  a[2]);
    float m1 = fminf(fminf(a[3],  a[4]),  a[5]);
    float m2 = fminf(fminf(a[6],  a[7]),  a[8]);
    float m3 = fminf(fminf(a[9],  a[10]), a[11]);
    float m4 = fminf(fminf(a[12], a[13]), a[14]);
    return fminf(fminf(fminf(m0, m1), m2), fminf(fminf(m3, m4), a[15]));
}

__device__ __forceinline__ void pack_b(const float* __restrict__ cp,
                                       half8& lo, half8& hi)
{
    float cx = cp[0], cy = cp[1], cz = cp[2];
    float x = -2.f * cx, y = -2.f * cy, z = -2.f * cz;
    float sq = fmaf(cx, cx, fmaf(cy, cy, cz * cz));
    _Float16 xh = (_Float16)x, yh = (_Float16)y, zh = (_Float16)z;
    _Float16 xl = (_Float16)(x - (float)xh);
    _Float16 yl = (_Float16)(y - (float)yh);
    _Float16 zl = (_Float16)(z - (float)zh);
    _Float16 sh = (_Float16)sq, sl = (_Float16)(sq - (float)sh);
    lo = half8{xh, yh, zh, xh, yh, zh, xl, yl};
    hi = half8{zl, (_Float16)1.f, (_Float16)1.f, sh, sl,
               (_Float16)0.f, (_Float16)0.f, (_Float16)0.f};
}

__device__ __forceinline__ half8 pack_a(const float* __restrict__ a, int half)
{
    float x = a[0], y = a[1], z = a[2];
    float sq = fmaf(x, x, fmaf(y, y, z * z));
    _Float16 xh = (_Float16)x, yh = (_Float16)y, zh = (_Float16)z;
    _Float16 xl = (_Float16)(x - (float)xh);
    _Float16 yl = (_Float16)(y - (float)yh);
    _Float16 zl = (_Float16)(z - (float)zh);
    _Float16 sh = (_Float16)sq, sl = (_Float16)(sq - (float)sh);
    half8 lo = {xh, yh, zh, xl, yl, zl, xh, yh};
    half8 hi = {zh, sh, sl, (_Float16)1.f, (_Float16)1.f,
                (_Float16)0.f, (_Float16)0.f, (_Float16)0.f};
    return half ? hi : lo;
}

// grid (32, 4, 8), block 256 (4 waves, each owning rows {g0, g0+128}).
// dist1 (min over m) in regs -> d1p[b][mh][n]  (unclamped).
// dist2 (min over wave's 64 rows) -> d2p[b][strip*4+wave][m] (clamped).
__global__ __launch_bounds__(256) void chamfer_mfma(
    const float* __restrict__ in1, const float* __restrict__ in2,
    float* __restrict__ d1p, float* __restrict__ d2p, float* __restrict__ out)
{
    const int b     = blockIdx.z;
    const int strip = blockIdx.x;
    const int mh    = blockIdx.y;
    const int wave  = threadIdx.x >> 6;
    const int lane  = threadIdx.x & 63;
    const int col   = lane & 31;
    const int half  = lane >> 5;

    if ((blockIdx.x | blockIdx.y | blockIdx.z) == 0 && threadIdx.x == 0)
        *out = 0.0f;                   // zero accumulator before reduce runs

    __shared__ _Float16 ldsLo[CHUNK * 8];      // 4 KiB
    __shared__ _Float16 ldsHi[CHUNK * 8];      // 4 KiB

    // Two A fragments per wave: rows nbase0.. and nbase0+128..
    const int nbase0 = strip * NSTRIP + wave * 32;
    const int nbase1 = nbase0 + 128;
    half8 afrag0 = pack_a(in1 + ((size_t)b * NPTS + nbase0 + col) * 3, half);
    half8 afrag1 = pack_a(in1 + ((size_t)b * NPTS + nbase1 + col) * 3, half);

    f16x MN0, MN1, zero;
#pragma unroll
    for (int r = 0; r < 16; ++r) { MN0[r] = 1e30f; MN1[r] = 1e30f; zero[r] = 0.0f; }

    const float* Craw = in2 + ((size_t)b * NPTS + mh * MHALF) * 3;
    float* d2w = d2p + ((size_t)b * NPL + strip * 4 + wave) * NPTS + mh * MHALF;

    // Pipelined pack: regs hold chunk c's packed point (1 per thread).
    half8 lo0, hi0;
    pack_b(Craw + (size_t)threadIdx.x * 3, lo0, hi0);

    for (int c = 0; c < NCHUNK; ++c) {
        __syncthreads();               // previous chunk's compute done
        *(half8*)&ldsLo[threadIdx.x * 8] = lo0;
        *(half8*)&ldsHi[threadIdx.x * 8] = hi0;
        __syncthreads();

        if (c + 1 < NCHUNK)            // next chunk's loads overlap compute
            pack_b(Craw + (size_t)((c + 1) * CHUNK + threadIdx.x) * 3, lo0, hi0);

        const _Float16* fragBase = half ? ldsHi : ldsLo;
#pragma unroll
        for (int t = 0; t < CHUNK / 32; ++t) {
            half8 bf = *(const half8*)&fragBase[(t * 32 + col) * 8];
            f16x acc0 = __builtin_amdgcn_mfma_f32_32x32x16_f16(afrag0, bf, zero, 0, 0, 0);
            f16x acc1 = __builtin_amdgcn_mfma_f32_32x32x16_f16(afrag1, bf, zero, 0, 0, 0);

            // dist1: per-reg running min across m (separate row-groups).
#pragma unroll
            for (int r = 0; r < 16; ++r) {
                MN0[r] = fminf(MN0[r], acc0[r]);
                MN1[r] = fminf(MN1[r], acc1[r]);
            }

            // dist2: column-min over both row-groups, merge halves via
            // shfl, single coalesced global store (each col written once).
            float v = fminf(colmin16(acc0), colmin16(acc1));
            v = fminf(v, __shfl_xor(v, 32, 64));
            if (half == 0)
                d2w[c * CHUNK + t * 32 + col] = fmaxf(v, 0.0f);
        }
    }

    // dist1: butterfly min across the 32 cols of each half, lane 0 of each
    // half writes its 16 rows: row = (r&3) + 8*(r>>2) + 4*half.
#pragma unroll
    for (int m = 1; m <= 16; m <<= 1)
#pragma unroll
        for (int r = 0; r < 16; ++r) {
            MN0[r] = fminf(MN0[r], __shfl_xor(MN0[r], m, 64));
            MN1[r] = fminf(MN1[r], __shfl_xor(MN1[r], m, 64));
        }
    if (col == 0) {
        float* d1 = d1p + ((size_t)b * NMH + mh) * NPTS;
#pragma unroll
        for (int r = 0; r < 16; ++r) {
            int row = (r & 3) + 8 * (r >> 2) + 4 * half;
            d1[nbase0 + row] = MN0[r];
            d1[nbase1 + row] = MN1[r];
        }
    }
}

// One thread per 4 m's: fold 128 d2 planes (pre-clamped) + 4 d1 planes
// (clamp here), sum, wave-reduce, atomicAdd(out, sum/TOTAL).
__global__ __launch_bounds__(256) void reduce_kernel(
    const float* __restrict__ d1p, const float* __restrict__ d2p,
    float* __restrict__ out)
{
    int g  = blockIdx.x * 256 + threadIdx.x;      // [0, TOTAL/4)
    int b  = g >> 11;
    int mq = g & 2047;                            // float4 index within batch

    const float4* p2 = (const float4*)(d2p + (size_t)b * NPL * NPTS) + mq;
    float4 v2 = p2[0];
#pragma unroll 8
    for (int s = 1; s < NPL; ++s) {
        float4 t = p2[(size_t)s * (NPTS / 4)];
        v2.x = fminf(v2.x, t.x); v2.y = fminf(v2.y, t.y);
        v2.z = fminf(v2.z, t.z); v2.w = fminf(v2.w, t.w);
    }
    float4 a0 = ((const float4*)(d1p + ((size_t)b * NMH + 0) * NPTS))[mq];
    float4 a1 = ((const float4*)(d1p + ((size_t)b * NMH + 1) * NPTS))[mq];
    float4 a2 = ((const float4*)(d1p + ((size_t)b * NMH + 2) * NPTS))[mq];
    float4 a3 = ((const float4*)(d1p + ((size_t)b * NMH + 3) * NPTS))[mq];
    float v = fmaxf(fminf(fminf(a0.x, a1.x), fminf(a2.x, a3.x)), 0.0f)
            + fmaxf(fminf(fminf(a0.y, a1.y), fminf(a2.y, a3.y)), 0.0f)
            + fmaxf(fminf(fminf(a0.z, a1.z), fminf(a2.z, a3.z)), 0.0f)
            + fmaxf(fminf(fminf(a0.w, a1.w), fminf(a2.w, a3.w)), 0.0f)
            + v2.x + v2.y + v2.z + v2.w;

#pragma unroll
    for (int off = 32; off; off >>= 1)
        v += __shfl_down(v, off, 64);
    __shared__ float wsum[4];
    int lane = threadIdx.x & 63, w = threadIdx.x >> 6;
    if (lane == 0) wsum[w] = v;
    __syncthreads();
    if (threadIdx.x == 0)
        atomicAdd(out, (wsum[0] + wsum[1] + wsum[2] + wsum[3]) *
                           (1.0f / (float)TOTAL));
}

extern "C" void kernel_launch(void* const* d_in, const int* in_sizes, int n_in,
                              void* d_out, int out_size, void* d_ws, size_t ws_size,
                              hipStream_t stream)
{
    const float* in1 = (const float*)d_in[0];
    const float* in2 = (const float*)d_in[1];
    float* out = (float*)d_out;

    char* ws = (char*)d_ws;
    float* d1p = (float*)ws;                              // 8*4*8192*4 = 1 MiB
    float* d2p = (float*)(ws + (size_t)NMH * TOTAL * 4);  // 8*128*8192*4 = 32 MiB

    chamfer_mfma<<<dim3(NPTS / NSTRIP, NMH, B), 256, 0, stream>>>(
        in1, in2, d1p, d2p, out);
    reduce_kernel<<<TOTAL / 1024, 256, 0, stream>>>(d1p, d2p, out);
}

// Round 11
// 94.090 us; speedup vs baseline: 8.5192x; 1.7649x over previous
//
#include <hip/hip_runtime.h>

// Chamfer distance, B=8, N=M=8192, D=3, fp32 — fused MFMA formulation.
// fp32 split into f16 hi+lo (x = xh+xl, err ~2^-22). K=16 vectors:
//   A(n): [ah0,ah1,ah2, al0,al1,al2, ah0,ah1,ah2, sqh_n,sql_n, 1,1, 0,0,0]
//   B(m): [bh0,bh1,bh2, bh0,bh1,bh2, bl0,bl1,bl2, 1,1, sqh_m,sql_m, 0,0,0]
// with b = -2c (exact). One v_mfma_f32_32x32x16_f16 = 32x32 tile of
// d(n,m) = sq_n + sq_m - 2<a,c> (+O(1e-5)); each tile feeds BOTH mins.
// R11 = R7 skeleton (best measured: VGPR 36, 8-wave blocks) + two fixes:
//   (1) MHALF 4096->2048: grid 1024 blocks -> 4 blocks/CU = 32 waves/CU
//       (R7 ran only 2 blocks/CU — grid-limited residency);
//   (2) lo/hi split LDS staging (16B stride, R8-verified 0 conflicts;
//       R7's 32B-stride pack writes caused 2.6M 4-way conflicts).
// R9 lesson: no forced min-waves __launch_bounds__ (spill risk).
// C/D: col=lane&31, row=(reg&3)+8*(reg>>2)+4*(lane>>5)  [HW-verified]
// A/B: row/col=lane&31, k=(lane>>5)*8+j                 [verified R5: absmax 0]

typedef _Float16 half8 __attribute__((ext_vector_type(8)));
typedef float    f16x  __attribute__((ext_vector_type(16)));

constexpr int B      = 8;
constexpr int NPTS   = 8192;
constexpr int TOTAL  = B * NPTS;      // 65536
constexpr int NSTRIP = 256;           // n-rows per block (8 waves * 32)
constexpr int NSTR   = NPTS / NSTRIP; // 32 strips
constexpr int MHALF  = 2048;          // m-range per block
constexpr int NMH    = NPTS / MHALF;  // 4
constexpr int CHUNK  = 512;           // m staged in LDS per chunk
constexpr int NCHUNK = MHALF / CHUNK; // 4

// min3 tree: min of 16 C-regs (column-min within a lane), 8 issues.
__device__ __forceinline__ float colmin16(const f16x& a)
{
    float m0 = fminf(fminf(a[0],  a[1]),  a[2]);
    float m1 = fminf(fminf(a[3],  a[4]),  a[5]);
    float m2 = fminf(fminf(a[6],  a[7]),  a[8]);
    float m3 = fminf(fminf(a[9],  a[10]), a[11]);
    float m4 = fminf(fminf(a[12], a[13]), a[14]);
    return fminf(fminf(fminf(m0, m1), m2), fminf(fminf(m3, m4), a[15]));
}

// grid (32, 4, 8), block 512 (8 waves x 32 n-rows).
// dist1 (min over m) folded in regs -> d1p[b][mh][n]  (unclamped).
// dist2 (min over n) via LDS atomicMin -> d2p[b][strip][m] (clamped).
__global__ __launch_bounds__(512) void chamfer_mfma(
    const float* __restrict__ in1, const float* __restrict__ in2,
    float* __restrict__ d1p, float* __restrict__ d2p, float* __restrict__ out)
{
    const int b     = blockIdx.z;
    const int strip = blockIdx.x;
    const int mh    = blockIdx.y;
    const int wave  = threadIdx.x >> 6;
    const int lane  = threadIdx.x & 63;
    const int col   = lane & 31;
    const int half  = lane >> 5;

    if ((blockIdx.x | blockIdx.y | blockIdx.z) == 0 && threadIdx.x == 0)
        *out = 0.0f;                   // zero accumulator before reduce runs

    __shared__ _Float16 ldsLo[CHUNK * 8];      // 8 KiB — 16B-stride writes
    __shared__ _Float16 ldsHi[CHUNK * 8];      // 8 KiB
    __shared__ unsigned d2lds[MHALF];          // 8 KiB

    for (int i = threadIdx.x; i < MHALF; i += 512)
        d2lds[i] = 0xFFFFFFFFu;

    // A fragment, packed in-register from raw in1.
    const int nbase = strip * NSTRIP + wave * 32;
    half8 afrag;
    {
        const float* a = in1 + ((size_t)b * NPTS + nbase + col) * 3;
        float x = a[0], y = a[1], z = a[2];
        float sq = fmaf(x, x, fmaf(y, y, z * z));
        _Float16 xh = (_Float16)x, yh = (_Float16)y, zh = (_Float16)z;
        _Float16 xl = (_Float16)(x - (float)xh);
        _Float16 yl = (_Float16)(y - (float)yh);
        _Float16 zl = (_Float16)(z - (float)zh);
        _Float16 sh = (_Float16)sq, sl = (_Float16)(sq - (float)sh);
        half8 lo = {xh, yh, zh, xl, yl, zl, xh, yh};
        half8 hi = {zh, sh, sl, (_Float16)1.f, (_Float16)1.f,
                    (_Float16)0.f, (_Float16)0.f, (_Float16)0.f};
        afrag = half ? hi : lo;
    }

    f16x MN1, zero;
#pragma unroll
    for (int r = 0; r < 16; ++r) { MN1[r] = 1e30f; zero[r] = 0.0f; }

    const float* Craw = in2 + ((size_t)b * NPTS + mh * MHALF) * 3;

    for (int c = 0; c < NCHUNK; ++c) {
        __syncthreads();
        // Stage + pack one candidate per thread into split lo/hi LDS.
        {
            const float* cp = Craw + (size_t)(c * CHUNK + threadIdx.x) * 3;
            float cx = cp[0], cy = cp[1], cz = cp[2];
            float x = -2.f * cx, y = -2.f * cy, z = -2.f * cz;
            float sq = fmaf(cx, cx, fmaf(cy, cy, cz * cz));
            _Float16 xh = (_Float16)x, yh = (_Float16)y, zh = (_Float16)z;
            _Float16 xl = (_Float16)(x - (float)xh);
            _Float16 yl = (_Float16)(y - (float)yh);
            _Float16 zl = (_Float16)(z - (float)zh);
            _Float16 sh = (_Float16)sq, sl = (_Float16)(sq - (float)sh);
            half8 lo = {xh, yh, zh, xh, yh, zh, xl, yl};
            half8 hi = {zl, (_Float16)1.f, (_Float16)1.f, sh, sl,
                        (_Float16)0.f, (_Float16)0.f, (_Float16)0.f};
            *(half8*)&ldsLo[threadIdx.x * 8] = lo;
            *(half8*)&ldsHi[threadIdx.x * 8] = hi;
        }
        __syncthreads();

        const _Float16* fragBase = half ? ldsHi : ldsLo;
#pragma unroll 2
        for (int t = 0; t < CHUNK / 32; t += 2) {
            half8 bfA = *(const half8*)&fragBase[((t    ) * 32 + col) * 8];
            half8 bfB = *(const half8*)&fragBase[((t + 1) * 32 + col) * 8];
            f16x accA = __builtin_amdgcn_mfma_f32_32x32x16_f16(afrag, bfA, zero, 0, 0, 0);
            f16x accB = __builtin_amdgcn_mfma_f32_32x32x16_f16(afrag, bfB, zero, 0, 0, 0);

            // dist1: per-reg running min across m (v_min3 per reg).
#pragma unroll
            for (int r = 0; r < 16; ++r)
                MN1[r] = fminf(fminf(MN1[r], accA[r]), accB[r]);

            // dist2: column-min of each tile, clamp, LDS atomicMin.
            float vA = fmaxf(colmin16(accA), 0.0f);
            atomicMin(&d2lds[c * CHUNK + t * 32 + col], __float_as_uint(vA));
            float vB = fmaxf(colmin16(accB), 0.0f);
            atomicMin(&d2lds[c * CHUNK + (t + 1) * 32 + col], __float_as_uint(vB));
        }
    }
    __syncthreads();

    float* d2 = d2p + ((size_t)b * NSTR + strip) * NPTS + mh * MHALF;
    for (int i = threadIdx.x; i < MHALF; i += 512)
        d2[i] = __uint_as_float(d2lds[i]);

    // dist1: butterfly min across the 32 cols of each half, lane 0 of each
    // half writes its 16 rows: row = (r&3) + 8*(r>>2) + 4*half.
#pragma unroll
    for (int m = 1; m <= 16; m <<= 1)
#pragma unroll
        for (int r = 0; r < 16; ++r)
            MN1[r] = fminf(MN1[r], __shfl_xor(MN1[r], m, 64));
    if (col == 0) {
        float* d1 = d1p + ((size_t)b * NMH + mh) * NPTS;
#pragma unroll
        for (int r = 0; r < 16; ++r)
            d1[nbase + (r & 3) + 8 * (r >> 2) + 4 * half] = MN1[r];
    }
}

// One thread per 4 m's: fold 32 d2 strip-planes (pre-clamped) + 4 d1
// planes (clamp here), sum, wave-reduce, atomicAdd(out, sum/TOTAL).
__global__ __launch_bounds__(256) void reduce_kernel(
    const float* __restrict__ d1p, const float* __restrict__ d2p,
    float* __restrict__ out)
{
    int g  = blockIdx.x * 256 + threadIdx.x;      // [0, TOTAL/4)
    int b  = g >> 11;
    int mq = g & 2047;                            // float4 index within batch

    const float4* p2 = (const float4*)(d2p + (size_t)b * NSTR * NPTS) + mq;
    float4 v2 = p2[0];
#pragma unroll
    for (int s = 1; s < NSTR; ++s) {
        float4 t = p2[(size_t)s * (NPTS / 4)];
        v2.x = fminf(v2.x, t.x); v2.y = fminf(v2.y, t.y);
        v2.z = fminf(v2.z, t.z); v2.w = fminf(v2.w, t.w);
    }
    float4 a0 = ((const float4*)(d1p + ((size_t)b * NMH + 0) * NPTS))[mq];
    float4 a1 = ((const float4*)(d1p + ((size_t)b * NMH + 1) * NPTS))[mq];
    float4 a2 = ((const float4*)(d1p + ((size_t)b * NMH + 2) * NPTS))[mq];
    float4 a3 = ((const float4*)(d1p + ((size_t)b * NMH + 3) * NPTS))[mq];
    float v = fmaxf(fminf(fminf(a0.x, a1.x), fminf(a2.x, a3.x)), 0.0f)
            + fmaxf(fminf(fminf(a0.y, a1.y), fminf(a2.y, a3.y)), 0.0f)
            + fmaxf(fminf(fminf(a0.z, a1.z), fminf(a2.z, a3.z)), 0.0f)
            + fmaxf(fminf(fminf(a0.w, a1.w), fminf(a2.w, a3.w)), 0.0f)
            + v2.x + v2.y + v2.z + v2.w;

#pragma unroll
    for (int off = 32; off; off >>= 1)
        v += __shfl_down(v, off, 64);
    __shared__ float wsum[4];
    int lane = threadIdx.x & 63, w = threadIdx.x >> 6;
    if (lane == 0) wsum[w] = v;
    __syncthreads();
    if (threadIdx.x == 0)
        atomicAdd(out, (wsum[0] + wsum[1] + wsum[2] + wsum[3]) *
                           (1.0f / (float)TOTAL));
}

extern "C" void kernel_launch(void* const* d_in, const int* in_sizes, int n_in,
                              void* d_out, int out_size, void* d_ws, size_t ws_size,
                              hipStream_t stream)
{
    const float* in1 = (const float*)d_in[0];
    const float* in2 = (const float*)d_in[1];
    float* out = (float*)d_out;

    char* ws = (char*)d_ws;
    float* d1p = (float*)ws;                              // 4*TOTAL*4 = 1 MiB
    float* d2p = (float*)(ws + (size_t)NMH * TOTAL * 4);  // 32*TOTAL*4 = 8 MiB

    chamfer_mfma<<<dim3(NPTS / NSTRIP, NMH, B), 512, 0, stream>>>(
        in1, in2, d1p, d2p, out);
    reduce_kernel<<<TOTAL / 1024, 256, 0, stream>>>(d1p, d2p, out);
}